// Round 11
// baseline (17424.806 us; speedup 1.0000x reference)
//
#include <hip/hip_runtime.h>

// Problem constants
constexpr int nB = 32, nT = 4096, nK = 256, nTP = 1024;

__device__ __forceinline__ float sigmoidf_(float x) { return 1.f / (1.f + expf(-x)); }

typedef unsigned int u32x4 __attribute__((ext_vector_type(4)));

// write-through stores: sc0 sc1 -> visible at device coherence point (memory-side)
__device__ __forceinline__ void store_u32_wt(unsigned* p, unsigned v) {
  asm volatile("global_store_dword %0, %1, off sc0 sc1" :: "v"(p), "v"(v) : "memory");
}
__device__ __forceinline__ void store_f32_wt(float* p, float v) {
  asm volatile("global_store_dword %0, %1, off sc0 sc1" :: "v"(p), "v"(v) : "memory");
}
__device__ __forceinline__ unsigned load_u32_wt(const unsigned* p) {
  unsigned v;
  asm volatile("global_load_dword %0, %1, off sc0 sc1\n\ts_waitcnt vmcnt(0)"
               : "=&v"(v) : "v"(p) : "memory");
  return v;
}

// cross-lane helpers: bit-identical replacements for __shfl_xor(x, m, 32)
__device__ __forceinline__ float dpp_xor1(float x) {
  return __int_as_float(__builtin_amdgcn_update_dpp(0, __float_as_int(x), 0xB1, 0xF, 0xF, true));
}
__device__ __forceinline__ float dpp_xor2(float x) {
  return __int_as_float(__builtin_amdgcn_update_dpp(0, __float_as_int(x), 0x4E, 0xF, 0xF, true));
}
__device__ __forceinline__ float dpp_xor8(float x) {
  return __int_as_float(__builtin_amdgcn_update_dpp(0, __float_as_int(x), 0x128, 0xF, 0xF, true));
}
__device__ __forceinline__ float swz_xor4(float x) {
  return __int_as_float(__builtin_amdgcn_ds_swizzle(__float_as_int(x), 0x101F));
}
__device__ __forceinline__ float swz_xor16(float x) {
  return __int_as_float(__builtin_amdgcn_ds_swizzle(__float_as_int(x), 0x401F));
}

// ---------------- tokenizer (unchanged, verified absmax 0) ----------------

__global__ __launch_bounds__(256) void k_mean(const float* __restrict__ x, float* __restrict__ sig) {
  int row = blockIdx.x * 4 + (threadIdx.x >> 6);
  int lane = threadIdx.x & 63;
  float v = x[(size_t)row * 64 + lane];
  #pragma unroll
  for (int off = 32; off > 0; off >>= 1) v += __shfl_down(v, off, 64);
  if (lane == 0) sig[row] = v * (1.0f / 64.0f);
}

__global__ __launch_bounds__(256) void k_conv1(const float* __restrict__ sig,
    const float* __restrict__ w1, const float* __restrict__ b1, float* __restrict__ h1) {
  int idx = blockIdx.x * 256 + threadIdx.x;
  int o = idx & 2047;
  int co = (idx >> 11) & 63;
  int b = idx >> 17;
  const float* s = sig + (size_t)b * nT;
  float acc = b1[co];
  int base = 2 * o - 1;
  #pragma unroll
  for (int j = 0; j < 4; j++) {
    int p = base + j;
    float sv = (p >= 0 && p < nT) ? s[p] : 0.f;
    acc = fmaf(w1[co * 4 + j], sv, acc);
  }
  h1[idx] = fmaxf(acc, 0.f);
}

__global__ __launch_bounds__(256) void k_conv2(const float* __restrict__ h1,
    const float* __restrict__ w2, const float* __restrict__ b2, float* __restrict__ h2) {
  int blk = blockIdx.x;
  int otile = blk & 3, co = (blk >> 2) & 63, b = blk >> 8;
  int o = otile * 256 + threadIdx.x;
  __shared__ float w[256];
  w[threadIdx.x] = w2[co * 256 + threadIdx.x];
  __syncthreads();
  const float* hin = h1 + (size_t)b * 64 * 2048;
  float acc = b2[co];
  int base = 2 * o - 1;
  for (int ci = 0; ci < 64; ci++) {
    const float* r = hin + ci * 2048;
    const float* wc = w + ci * 4;
    #pragma unroll
    for (int j = 0; j < 4; j++) {
      int p = base + j;
      float v = (p >= 0 && p < 2048) ? r[p] : 0.f;
      acc = fmaf(wc[j], v, acc);
    }
  }
  h2[((size_t)b * 64 + co) * 1024 + o] = fmaxf(acc, 0.f);
}

__global__ __launch_bounds__(256) void k_conv3(const float* __restrict__ h2,
    const float* __restrict__ w3, const float* __restrict__ b3, float* __restrict__ ze) {
  int blk = blockIdx.x;
  int otile = blk & 3, co = (blk >> 2) & 63, b = blk >> 8;
  int o = otile * 256 + threadIdx.x;
  __shared__ float w[192];
  if (threadIdx.x < 192) w[threadIdx.x] = w3[co * 192 + threadIdx.x];
  __syncthreads();
  const float* hin = h2 + (size_t)b * 64 * 1024;
  float acc = b3[co];
  for (int ci = 0; ci < 64; ci++) {
    const float* r = hin + ci * 1024;
    const float* wc = w + ci * 3;
    #pragma unroll
    for (int j = 0; j < 3; j++) {
      int p = o - 1 + j;
      float v = (p >= 0 && p < 1024) ? r[p] : 0.f;
      acc = fmaf(wc[j], v, acc);
    }
  }
  ze[((size_t)b * 64 + co) * 1024 + o] = acc;
}

__global__ __launch_bounds__(256) void k_cbnorm(const float* __restrict__ cb, float* __restrict__ cbn) {
  int k = threadIdx.x;
  const float4* c4 = (const float4*)(cb + (size_t)k * 64);
  float acc = 0.f;
  #pragma unroll
  for (int q = 0; q < 16; q++) {
    float4 e = c4[q];
    acc = fmaf(e.x, e.x, fmaf(e.y, e.y, fmaf(e.z, e.z, fmaf(e.w, e.w, acc))));
  }
  cbn[k] = acc;
}

__global__ __launch_bounds__(256) void k_vq(const float* __restrict__ ze,
    const float* __restrict__ cb, const float* __restrict__ cbn, float* __restrict__ zq) {
  __shared__ float scb[nK * 64];
  for (int i = threadIdx.x; i < nK * 64; i += 256) scb[i] = cb[i];
  __syncthreads();
  int g = blockIdx.x * 256 + threadIdx.x;
  int b = g >> 10, o = g & 1023;
  const float* zb = ze + (size_t)b * 64 * 1024 + o;
  float z[64];
  #pragma unroll
  for (int d = 0; d < 64; d++) z[d] = zb[(size_t)d * 1024];
  float best = 3.4e38f; int bi = 0;
  for (int k = 0; k < nK; k++) {
    const float4* ck = (const float4*)(scb + k * 64);
    float dot = 0.f;
    #pragma unroll
    for (int q = 0; q < 16; q++) {
      float4 c4 = ck[q];
      dot = fmaf(c4.x, z[4 * q + 0], dot);
      dot = fmaf(c4.y, z[4 * q + 1], dot);
      dot = fmaf(c4.z, z[4 * q + 2], dot);
      dot = fmaf(c4.w, z[4 * q + 3], dot);
    }
    float s = cbn[k] - 2.f * dot;
    if (s < best) { best = s; bi = k; }
  }
  float4* zo4 = (float4*)(zq + (size_t)g * 64);
  const float4* cbest = (const float4*)(scb + bi * 64);
  #pragma unroll
  for (int q = 0; q < 16; q++) zo4[q] = cbest[q];
}

// transpose zq [b][t][d] -> zqT [t][d][b]
__global__ __launch_bounds__(256) void k_zqt(const float* __restrict__ zq, float* __restrict__ zqT) {
  int t = blockIdx.x;
  for (int o = threadIdx.x; o < 2048; o += 256) {
    int d = o >> 5, b = o & 31;
    zqT[(size_t)t * 2048 + o] = zq[((size_t)b * nTP + t) * 64 + d];
  }
}

// ---------------- persistent fused 2-layer LSTM + head ----------------
// Round-17: SKEW + MASTER/RELEASE (completing the 2x2). r16 (15.2ms) proved
// the flat poll storm cost ~1.3ms; r10's skew regression (-4.9ms) carried TWO
// flat poll rounds/step (~+4.8us/step contention) -> skew structure itself
// untested. Steady-state period: relay + max(stage+L0, L1) vs single-barrier's
// stage+L0+L1+2*relay: rel0 (top-wait guard, h0[t-1] + WAR) is released at
// MID-iter (slack = L1 phase); rel1 (mid-wait guard, h1[t-2]) released at END
// (slack = stage+L0). Triple-buffer mod-3 (r10 indexing, audit re-verified).
// Compute bodies byte-identical to r16; vbuf stays inside the L1 phase (no
// reg array crosses a barrier); poll asm =&v; private release lines per block.

__global__ __launch_bounds__(512, 2) void k_lstm(
    const float* __restrict__ zqT,
    const float* __restrict__ wih0, const float* __restrict__ whh0, const float* __restrict__ bl0,
    const float* __restrict__ wih1, const float* __restrict__ whh1, const float* __restrict__ bl1,
    const float* __restrict__ wout, const float* __restrict__ bout,
    float* __restrict__ st, float* __restrict__ out)
{
  __shared__ float wB [2][4][32][36];
  __shared__ float wAh[2][4][32][20];
  __shared__ float wAz[2][4][64];
  __shared__ float wHd[2][512];
  __shared__ float bHd[2];
  __shared__ float h0s[16384];   // staged h0[t-1], XOR-swizzled [512][32]

  float* h0T = st;                            // [3][512][32]
  float* h1T = st + 49152;                    // [3][512][32]
  unsigned* flags0 = (unsigned*)(st + 98304); // [256] arrival L0 (pad 1024)
  unsigned* flags1 = flags0 + 1024;           // [256] arrival end (pad 1024)
  unsigned* rel0   = flags1 + 1024;           // [256*16] private release lines
  unsigned* rel1   = rel0 + 4096;             // [256*16]

  const int blk = blockIdx.x;
  const int tid = threadIdx.x;
  const int dim = tid >> 8;
  const int bg  = (tid >> 5) & 7;
  const int c   = tid & 31;
  const int b0  = bg * 4;
  const int j   = 2 * blk + dim;

  // ---- stage weights into LDS ----
  for (int idx = tid; idx < 2 * 4 * 32 * 32; idx += 512) {
    int k = idx & 31, cc = (idx >> 5) & 31, gg = (idx >> 10) & 3, dd = idx >> 12;
    int row = gg * 512 + 2 * blk + dd;
    float v = (cc < 16) ? whh1[(size_t)row * 512 + cc * 32 + k]
                        : wih1[(size_t)row * 512 + (cc - 16) * 32 + k];
    wB[dd][gg][cc][k] = v;
  }
  for (int idx = tid; idx < 2 * 4 * 32 * 16; idx += 512) {
    int k = idx & 15, cc = (idx >> 4) & 31, gg = (idx >> 9) & 3, dd = idx >> 11;
    wAh[dd][gg][cc][k] = whh0[(size_t)(gg * 512 + 2 * blk + dd) * 512 + cc * 16 + k];
  }
  if (tid < 512) {
    int d = tid & 63, gg = (tid >> 6) & 3, dd = tid >> 8;
    wAz[dd][gg][d] = wih0[(size_t)(gg * 512 + 2 * blk + dd) * 64 + d];
  }
  if (blk < 96) {
    for (int idx = tid; idx < 1024; idx += 512) {
      int q = idx >> 9, i = idx & 511;
      int p = blk * 2 + q;
      wHd[q][i] = wout[(size_t)(p >> 5) * 512 + i];
      if (i == 0) bHd[q] = bout[p >> 5];
    }
  }
  float bA[4], bB4[4];
  #pragma unroll
  for (int g = 0; g < 4; g++) { bA[g] = bl0[g * 512 + j]; bB4[g] = bl1[g * 512 + j]; }
  float creg0 = 0.f, creg1 = 0.f;   // cell state for (j, b0+c), lanes c<4 only
  __syncthreads();

  // per-lane swizzled LDS base pointers (swizzle bits 2-4; offsets use bits >=5)
  const float* h0vL0 = h0s + ((c * 512 + b0) ^ ((c & 7) << 2));
  const int cp = c - 16;
  const float* h0vA = h0s + (((cp < 0 ? 0 : cp) * 1024 + b0) ^ (((2 * (cp < 0 ? 0 : cp)) & 7) << 2));
  const float* h0vB = h0s + (((cp < 0 ? 0 : cp) * 1024 + 512 + b0) ^ (((2 * (cp < 0 ? 0 : cp) + 1) & 7) << 2));

  for (int t = 0; t <= nTP + 1; t++) {
    const int p  = t % 3;                        // h0 read buf (step t-1); h1 write buf (step t-1)
    const int pw = (p + 1 == 3) ? 0 : p + 1;     // h0 write buf (step t)
    const int pm = (p + 2 >= 3) ? p - 1 : p + 2; // h1 read buf (step t-2); head read buf

    // ---- TOP WAIT: rel0>=t (h0[t-1] visible + WAR) && rel1>=t-1 (iter t-2 readers done) ----
    if (t >= 1 && t <= nTP) {
      if (tid == 0) {
        unsigned tg0 = (unsigned)t, tg1 = (unsigned)(t - 1);
        const unsigned* rp0 = rel0 + blk * 16;
        const unsigned* rp1 = rel1 + blk * 16;
        while (load_u32_wt(rp0) < tg0) __builtin_amdgcn_s_sleep(1);
        while (load_u32_wt(rp1) < tg1) __builtin_amdgcn_s_sleep(1);
      }
      if (tid < 64) __builtin_amdgcn_fence(__ATOMIC_ACQUIRE, "agent");  // buffer_inv
      __syncthreads();
    }

    // ---- stage h0T[p] = h0[t-1] into swizzled LDS ----
    if (t <= nTP) {
      const float* src = h0T + p * 16384;
      #pragma unroll
      for (int q = 0; q < 8; q++) {
        int lin = (q * 512 + tid) * 4;
        float4 v = *(const float4*)(src + lin);
        int phys = lin ^ (((lin >> 9) & 7) << 2);
        *(float4*)&h0s[phys] = v;
      }
      __syncthreads();
    }

    // ---- L0 step t (h from LDS), write h0T[pw] ----
    if (t < nTP) {
      float acc[16];
      #pragma unroll
      for (int r = 0; r < 16; r++) acc[r] = 0.f;
      {
        #pragma unroll
        for (int s = 0; s < 4; s++) {
          float4 v0 = *(const float4*)(h0vL0 + (s * 4 + 0) * 32);
          float4 v1 = *(const float4*)(h0vL0 + (s * 4 + 1) * 32);
          float4 v2 = *(const float4*)(h0vL0 + (s * 4 + 2) * 32);
          float4 v3 = *(const float4*)(h0vL0 + (s * 4 + 3) * 32);
          #pragma unroll
          for (int g = 0; g < 4; g++) {
            float4 w = *(const float4*)&wAh[dim][g][c][s * 4];
            float* a = acc + g * 4;
            a[0]=fmaf(w.x,v0.x,a[0]); a[0]=fmaf(w.y,v1.x,a[0]); a[0]=fmaf(w.z,v2.x,a[0]); a[0]=fmaf(w.w,v3.x,a[0]);
            a[1]=fmaf(w.x,v0.y,a[1]); a[1]=fmaf(w.y,v1.y,a[1]); a[1]=fmaf(w.z,v2.y,a[1]); a[1]=fmaf(w.w,v3.y,a[1]);
            a[2]=fmaf(w.x,v0.z,a[2]); a[2]=fmaf(w.y,v1.z,a[2]); a[2]=fmaf(w.z,v2.z,a[2]); a[2]=fmaf(w.w,v3.z,a[2]);
            a[3]=fmaf(w.x,v0.w,a[3]); a[3]=fmaf(w.y,v1.w,a[3]); a[3]=fmaf(w.z,v2.w,a[3]); a[3]=fmaf(w.w,v3.w,a[3]);
          }
        }
      }
      {
        const float* zt = zqT + (size_t)t * 2048 + b0;
        float4 u0 = *(const float4*)(zt + (c * 2 + 0) * 32);
        float4 u1 = *(const float4*)(zt + (c * 2 + 1) * 32);
        #pragma unroll
        for (int g = 0; g < 4; g++) {
          float wx = wAz[dim][g][c * 2 + 0], wy = wAz[dim][g][c * 2 + 1];
          float* a = acc + g * 4;
          a[0]=fmaf(wx,u0.x,a[0]); a[0]=fmaf(wy,u1.x,a[0]);
          a[1]=fmaf(wx,u0.y,a[1]); a[1]=fmaf(wy,u1.y,a[1]);
          a[2]=fmaf(wx,u0.z,a[2]); a[2]=fmaf(wy,u1.z,a[2]);
          a[3]=fmaf(wx,u0.w,a[3]); a[3]=fmaf(wy,u1.w,a[3]);
        }
      }
      // reduce: same tree order m = 1,2,4,8,16 (bit-identical)
      #pragma unroll
      for (int r = 0; r < 16; r++) acc[r] += dpp_xor1(acc[r]);
      #pragma unroll
      for (int r = 0; r < 16; r++) acc[r] += dpp_xor2(acc[r]);
      #pragma unroll
      for (int r = 0; r < 16; r++) acc[r] += swz_xor4(acc[r]);
      #pragma unroll
      for (int r = 0; r < 16; r++) acc[r] += dpp_xor8(acc[r]);
      #pragma unroll
      for (int r = 0; r < 16; r++) acc[r] += swz_xor16(acc[r]);
      if (c < 4) {
        int b = b0 + c;
        float gi = sigmoidf_(acc[0 * 4 + c] + bA[0]);
        float gf = sigmoidf_(acc[1 * 4 + c] + bA[1]);
        float gg = tanhf    (acc[2 * 4 + c] + bA[2]);
        float go = sigmoidf_(acc[3 * 4 + c] + bA[3]);
        float cn = fmaf(gf, creg0, gi * gg);
        creg0 = cn;
        store_f32_wt(h0T + pw * 16384 + j * 32 + b, go * tanhf(cn));
      }
    }

    // ---- mid drain + post flags0 = t+1 (h0[t] stores + h0T[p] stage reads done) ----
    asm volatile("s_waitcnt vmcnt(0)" ::: "memory");
    __syncthreads();
    if (t < nTP && tid == 0) store_u32_wt(flags0 + blk, (unsigned)(t + 1));

    // ---- MASTER DUTY A (block 0): detect flags0>=t+1, broadcast rel0 ----
    if (t < nTP && blk == 0 && tid < 64) {
      unsigned tgt = (unsigned)(t + 1);
      const u32x4* fp = (const u32x4*)flags0 + tid;
      for (;;) {
        u32x4 f;
        asm volatile("global_load_dwordx4 %0, %1, off sc0 sc1\n\ts_waitcnt vmcnt(0)"
                     : "=&v"(f) : "v"(fp) : "memory");
        bool ok = (f.x >= tgt) && (f.y >= tgt) && (f.z >= tgt) && (f.w >= tgt);
        if (__all(ok)) break;
        __builtin_amdgcn_s_sleep(1);
      }
      unsigned* rp = rel0 + tid * 64;
      #pragma unroll
      for (int q = 0; q < 4; q++) store_u32_wt(rp + q * 16, tgt);
    }

    // ---- MID WAIT: rel1 >= t (h1[t-2] visible) ----
    if (t >= 1) {
      if (tid == 0) {
        unsigned tg1 = (unsigned)t;
        const unsigned* rp1 = rel1 + blk * 16;
        while (load_u32_wt(rp1) < tg1) __builtin_amdgcn_s_sleep(1);
      }
      if (tid < 64) __builtin_amdgcn_fence(__ATOMIC_ACQUIRE, "agent");  // buffer_inv
      __syncthreads();
    }

    // ---- L1 step t-1: h1T[pm] (global, in-phase vbuf) c<16; h0s (LDS) c>=16; write h1T[p] ----
    if (t >= 1 && t <= nTP) {
      const float* h1p = h1T + pm * 16384;
      float4 vbuf[32];
      if (c < 16) {
        const float* vg = h1p + c * 32 * 32 + b0;
        #pragma unroll
        for (int k = 0; k < 32; k++) vbuf[k] = *(const float4*)(vg + k * 32);
      } else {
        #pragma unroll
        for (int k = 0; k < 16; k++) vbuf[k] = *(const float4*)(h0vA + k * 32);
        #pragma unroll
        for (int k = 0; k < 16; k++) vbuf[16 + k] = *(const float4*)(h0vB + k * 32);
      }
      float acc[16];
      #pragma unroll
      for (int r = 0; r < 16; r++) acc[r] = 0.f;
      #pragma unroll
      for (int s = 0; s < 8; s++) {
        float4 v0 = vbuf[s * 4 + 0];
        float4 v1 = vbuf[s * 4 + 1];
        float4 v2 = vbuf[s * 4 + 2];
        float4 v3 = vbuf[s * 4 + 3];
        #pragma unroll
        for (int g = 0; g < 4; g++) {
          float4 w = *(const float4*)&wB[dim][g][c][s * 4];
          float* a = acc + g * 4;
          a[0]=fmaf(w.x,v0.x,a[0]); a[0]=fmaf(w.y,v1.x,a[0]); a[0]=fmaf(w.z,v2.x,a[0]); a[0]=fmaf(w.w,v3.x,a[0]);
          a[1]=fmaf(w.x,v0.y,a[1]); a[1]=fmaf(w.y,v1.y,a[1]); a[1]=fmaf(w.z,v2.y,a[1]); a[1]=fmaf(w.w,v3.y,a[1]);
          a[2]=fmaf(w.x,v0.z,a[2]); a[2]=fmaf(w.y,v1.z,a[2]); a[2]=fmaf(w.z,v2.z,a[2]); a[2]=fmaf(w.w,v3.z,a[2]);
          a[3]=fmaf(w.x,v0.w,a[3]); a[3]=fmaf(w.y,v1.w,a[3]); a[3]=fmaf(w.z,v2.w,a[3]); a[3]=fmaf(w.w,v3.w,a[3]);
        }
      }
      #pragma unroll
      for (int r = 0; r < 16; r++) acc[r] += dpp_xor1(acc[r]);
      #pragma unroll
      for (int r = 0; r < 16; r++) acc[r] += dpp_xor2(acc[r]);
      #pragma unroll
      for (int r = 0; r < 16; r++) acc[r] += swz_xor4(acc[r]);
      #pragma unroll
      for (int r = 0; r < 16; r++) acc[r] += dpp_xor8(acc[r]);
      #pragma unroll
      for (int r = 0; r < 16; r++) acc[r] += swz_xor16(acc[r]);
      if (c < 4) {
        int b = b0 + c;
        float gi = sigmoidf_(acc[0 * 4 + c] + bB4[0]);
        float gf = sigmoidf_(acc[1 * 4 + c] + bB4[1]);
        float gg = tanhf    (acc[2 * 4 + c] + bB4[2]);
        float go = sigmoidf_(acc[3 * 4 + c] + bB4[3]);
        float cn = fmaf(gf, creg1, gi * gg);
        creg1 = cn;
        store_f32_wt(h1T + p * 16384 + j * 32 + b, go * tanhf(cn));
      }
    }

    // ---- head for step t-2 (reads h1T[pm], covered by mid wait) ----
    if (t >= 2 && blk < 96 && tid >= 64 && tid < 80) {
      int q = (tid >> 3) & 1, l = tid & 7;
      int pp = blk * 2 + q;
      int b = pp & 31;
      const float* h1s = h1T + pm * 16384;
      float a = 0.f;
      #pragma unroll 8
      for (int m = 0; m < 64; m++) {
        int i = l * 64 + m;
        a = fmaf(wHd[q][i], h1s[i * 32 + b], a);
      }
      a += __shfl_down(a, 4, 8);
      a += __shfl_down(a, 2, 8);
      a += __shfl_down(a, 1, 8);
      if (l == 0) out[((size_t)b * nTP + (t - 2)) * 6 + (pp >> 5)] = a + bHd[q];
    }

    // ---- end drain + post flags1 = t+1 (h1[t-1] stores + all iter-t reads done) ----
    asm volatile("s_waitcnt vmcnt(0)" ::: "memory");
    __syncthreads();
    if (t <= nTP && tid == 0) store_u32_wt(flags1 + blk, (unsigned)(t + 1));

    // ---- MASTER DUTY B (block 0): detect flags1>=t+1, broadcast rel1 ----
    if (t <= nTP && blk == 0 && tid < 64) {
      unsigned tgt = (unsigned)(t + 1);
      const u32x4* fp = (const u32x4*)flags1 + tid;
      for (;;) {
        u32x4 f;
        asm volatile("global_load_dwordx4 %0, %1, off sc0 sc1\n\ts_waitcnt vmcnt(0)"
                     : "=&v"(f) : "v"(fp) : "memory");
        bool ok = (f.x >= tgt) && (f.y >= tgt) && (f.z >= tgt) && (f.w >= tgt);
        if (__all(ok)) break;
        __builtin_amdgcn_s_sleep(1);
      }
      unsigned* rp = rel1 + tid * 64;
      #pragma unroll
      for (int q = 0; q < 4; q++) store_u32_wt(rp + q * 16, tgt);
    }
  }
}

// ---------------- launch ----------------

extern "C" void kernel_launch(void* const* d_in, const int* in_sizes, int n_in,
                              void* d_out, int out_size, void* d_ws, size_t ws_size,
                              hipStream_t stream) {
  (void)in_sizes; (void)n_in; (void)out_size; (void)ws_size;
  const float* x    = (const float*)d_in[0];
  const float* w1   = (const float*)d_in[1];
  const float* b1   = (const float*)d_in[2];
  const float* w2   = (const float*)d_in[3];
  const float* b2   = (const float*)d_in[4];
  const float* w3   = (const float*)d_in[5];
  const float* b3   = (const float*)d_in[6];
  const float* cb   = (const float*)d_in[7];
  const float* wih0 = (const float*)d_in[8];
  const float* whh0 = (const float*)d_in[9];
  const float* bl0  = (const float*)d_in[10];
  const float* wih1 = (const float*)d_in[11];
  const float* whh1 = (const float*)d_in[12];
  const float* bl1  = (const float*)d_in[13];
  const float* wout = (const float*)d_in[14];
  const float* bout = (const float*)d_in[15];
  float* out = (float*)d_out;

  float* ws  = (float*)d_ws;
  // region reuse: st+flags overlaps sig (dead after conv1); zqT overlaps h1c (dead after conv2)
  float* sig = ws;                 // 131072 floats (later: h0T/h1T 3x16384 each + flags/rel)
  float* h1c = sig + 131072;       // 4194304  [32][64][2048] (later: zqT, 2097152)
  float* h2c = h1c + 4194304;      // 2097152  [32][64][1024]
  float* ze  = h2c + 2097152;      // 2097152  [32][64][1024]
  float* zq  = ze  + 2097152;      // 2097152  [32*1024][64]
  float* cbn = zq  + 2097152;      // 256
  float* stp = ws;                 // h0T[3], h1T[3], flags0/1[1024 ea], rel0/1[4096 ea]
  float* zqT = h1c;                // 2097152  [1024][64][32]

  k_mean <<<32768, 256, 0, stream>>>(x, sig);
  k_conv1<<<16384, 256, 0, stream>>>(sig, w1, b1, h1c);
  hipMemsetAsync(stp, 0, (98304 + 2048 + 8192) * sizeof(float), stream);  // state + flags + rel
  k_conv2<<<8192, 256, 0, stream>>>(h1c, w2, b2, h2c);
  k_conv3<<<8192, 256, 0, stream>>>(h2c, w3, b3, ze);
  k_cbnorm<<<1, 256, 0, stream>>>(cb, cbn);
  k_vq   <<<128, 256, 0, stream>>>(ze, cb, cbn, zq);
  k_zqt  <<<1024, 256, 0, stream>>>(zq, zqT);   // h1c dead now; write zqT over it

  void* kargs[] = { (void*)&zqT, (void*)&wih0, (void*)&whh0, (void*)&bl0,
                    (void*)&wih1, (void*)&whh1, (void*)&bl1,
                    (void*)&wout, (void*)&bout, (void*)&stp, (void*)&out };
  hipLaunchCooperativeKernel((void*)k_lstm, dim3(256), dim3(512), kargs, 0, stream);
}

// Round 12
// 14268.428 us; speedup vs baseline: 1.2212x; 1.2212x over previous
//
#include <hip/hip_runtime.h>

// Problem constants
constexpr int nB = 32, nT = 4096, nK = 256, nTP = 1024;

__device__ __forceinline__ float sigmoidf_(float x) { return 1.f / (1.f + expf(-x)); }

typedef unsigned int u32x4 __attribute__((ext_vector_type(4)));
typedef float f32x4v __attribute__((ext_vector_type(4)));

// write-through stores: sc0 sc1 -> visible at device coherence point (memory-side)
__device__ __forceinline__ void store_u32_wt(unsigned* p, unsigned v) {
  asm volatile("global_store_dword %0, %1, off sc0 sc1" :: "v"(p), "v"(v) : "memory");
}
__device__ __forceinline__ void store_f32_wt(float* p, float v) {
  asm volatile("global_store_dword %0, %1, off sc0 sc1" :: "v"(p), "v"(v) : "memory");
}
__device__ __forceinline__ unsigned load_u32_wt(const unsigned* p) {
  unsigned v;
  asm volatile("global_load_dword %0, %1, off sc0 sc1\n\ts_waitcnt vmcnt(0)"
               : "=&v"(v) : "v"(p) : "memory");
  return v;
}
// uncached (memory-side) loads, NO internal wait: caller batches then issues
// one s_waitcnt vmcnt(0) + sched_barrier(0) (guide rule #18) before consumers.
__device__ __forceinline__ f32x4v load_f32x4_wt_nw(const float* p) {
  f32x4v v;
  asm volatile("global_load_dwordx4 %0, %1, off sc0 sc1" : "=&v"(v) : "v"(p) : "memory");
  return v;
}
__device__ __forceinline__ float load_f32_wt_nw(const float* p) {
  float v;
  asm volatile("global_load_dword %0, %1, off sc0 sc1" : "=&v"(v) : "v"(p) : "memory");
  return v;
}

// cross-lane helpers: bit-identical replacements for __shfl_xor(x, m, 32)
__device__ __forceinline__ float dpp_xor1(float x) {
  return __int_as_float(__builtin_amdgcn_update_dpp(0, __float_as_int(x), 0xB1, 0xF, 0xF, true));
}
__device__ __forceinline__ float dpp_xor2(float x) {
  return __int_as_float(__builtin_amdgcn_update_dpp(0, __float_as_int(x), 0x4E, 0xF, 0xF, true));
}
__device__ __forceinline__ float dpp_xor8(float x) {
  return __int_as_float(__builtin_amdgcn_update_dpp(0, __float_as_int(x), 0x128, 0xF, 0xF, true));
}
__device__ __forceinline__ float swz_xor4(float x) {
  return __int_as_float(__builtin_amdgcn_ds_swizzle(__float_as_int(x), 0x101F));
}
__device__ __forceinline__ float swz_xor16(float x) {
  return __int_as_float(__builtin_amdgcn_ds_swizzle(__float_as_int(x), 0x401F));
}

// ---------------- tokenizer (unchanged, verified absmax 0) ----------------

__global__ __launch_bounds__(256) void k_mean(const float* __restrict__ x, float* __restrict__ sig) {
  int row = blockIdx.x * 4 + (threadIdx.x >> 6);
  int lane = threadIdx.x & 63;
  float v = x[(size_t)row * 64 + lane];
  #pragma unroll
  for (int off = 32; off > 0; off >>= 1) v += __shfl_down(v, off, 64);
  if (lane == 0) sig[row] = v * (1.0f / 64.0f);
}

__global__ __launch_bounds__(256) void k_conv1(const float* __restrict__ sig,
    const float* __restrict__ w1, const float* __restrict__ b1, float* __restrict__ h1) {
  int idx = blockIdx.x * 256 + threadIdx.x;
  int o = idx & 2047;
  int co = (idx >> 11) & 63;
  int b = idx >> 17;
  const float* s = sig + (size_t)b * nT;
  float acc = b1[co];
  int base = 2 * o - 1;
  #pragma unroll
  for (int j = 0; j < 4; j++) {
    int p = base + j;
    float sv = (p >= 0 && p < nT) ? s[p] : 0.f;
    acc = fmaf(w1[co * 4 + j], sv, acc);
  }
  h1[idx] = fmaxf(acc, 0.f);
}

__global__ __launch_bounds__(256) void k_conv2(const float* __restrict__ h1,
    const float* __restrict__ w2, const float* __restrict__ b2, float* __restrict__ h2) {
  int blk = blockIdx.x;
  int otile = blk & 3, co = (blk >> 2) & 63, b = blk >> 8;
  int o = otile * 256 + threadIdx.x;
  __shared__ float w[256];
  w[threadIdx.x] = w2[co * 256 + threadIdx.x];
  __syncthreads();
  const float* hin = h1 + (size_t)b * 64 * 2048;
  float acc = b2[co];
  int base = 2 * o - 1;
  for (int ci = 0; ci < 64; ci++) {
    const float* r = hin + ci * 2048;
    const float* wc = w + ci * 4;
    #pragma unroll
    for (int j = 0; j < 4; j++) {
      int p = base + j;
      float v = (p >= 0 && p < 2048) ? r[p] : 0.f;
      acc = fmaf(wc[j], v, acc);
    }
  }
  h2[((size_t)b * 64 + co) * 1024 + o] = fmaxf(acc, 0.f);
}

__global__ __launch_bounds__(256) void k_conv3(const float* __restrict__ h2,
    const float* __restrict__ w3, const float* __restrict__ b3, float* __restrict__ ze) {
  int blk = blockIdx.x;
  int otile = blk & 3, co = (blk >> 2) & 63, b = blk >> 8;
  int o = otile * 256 + threadIdx.x;
  __shared__ float w[192];
  if (threadIdx.x < 192) w[threadIdx.x] = w3[co * 192 + threadIdx.x];
  __syncthreads();
  const float* hin = h2 + (size_t)b * 64 * 1024;
  float acc = b3[co];
  for (int ci = 0; ci < 64; ci++) {
    const float* r = hin + ci * 1024;
    const float* wc = w + ci * 3;
    #pragma unroll
    for (int j = 0; j < 3; j++) {
      int p = o - 1 + j;
      float v = (p >= 0 && p < 1024) ? r[p] : 0.f;
      acc = fmaf(wc[j], v, acc);
    }
  }
  ze[((size_t)b * 64 + co) * 1024 + o] = acc;
}

__global__ __launch_bounds__(256) void k_cbnorm(const float* __restrict__ cb, float* __restrict__ cbn) {
  int k = threadIdx.x;
  const float4* c4 = (const float4*)(cb + (size_t)k * 64);
  float acc = 0.f;
  #pragma unroll
  for (int q = 0; q < 16; q++) {
    float4 e = c4[q];
    acc = fmaf(e.x, e.x, fmaf(e.y, e.y, fmaf(e.z, e.z, fmaf(e.w, e.w, acc))));
  }
  cbn[k] = acc;
}

__global__ __launch_bounds__(256) void k_vq(const float* __restrict__ ze,
    const float* __restrict__ cb, const float* __restrict__ cbn, float* __restrict__ zq) {
  __shared__ float scb[nK * 64];
  for (int i = threadIdx.x; i < nK * 64; i += 256) scb[i] = cb[i];
  __syncthreads();
  int g = blockIdx.x * 256 + threadIdx.x;
  int b = g >> 10, o = g & 1023;
  const float* zb = ze + (size_t)b * 64 * 1024 + o;
  float z[64];
  #pragma unroll
  for (int d = 0; d < 64; d++) z[d] = zb[(size_t)d * 1024];
  float best = 3.4e38f; int bi = 0;
  for (int k = 0; k < nK; k++) {
    const float4* ck = (const float4*)(scb + k * 64);
    float dot = 0.f;
    #pragma unroll
    for (int q = 0; q < 16; q++) {
      float4 c4 = ck[q];
      dot = fmaf(c4.x, z[4 * q + 0], dot);
      dot = fmaf(c4.y, z[4 * q + 1], dot);
      dot = fmaf(c4.z, z[4 * q + 2], dot);
      dot = fmaf(c4.w, z[4 * q + 3], dot);
    }
    float s = cbn[k] - 2.f * dot;
    if (s < best) { best = s; bi = k; }
  }
  float4* zo4 = (float4*)(zq + (size_t)g * 64);
  const float4* cbest = (const float4*)(scb + bi * 64);
  #pragma unroll
  for (int q = 0; q < 16; q++) zo4[q] = cbest[q];
}

// transpose zq [b][t][d] -> zqT [t][d][b]
__global__ __launch_bounds__(256) void k_zqt(const float* __restrict__ zq, float* __restrict__ zqT) {
  int t = blockIdx.x;
  for (int o = threadIdx.x; o < 2048; o += 256) {
    int d = o >> 5, b = o & 31;
    zqT[(size_t)t * 2048 + o] = zq[((size_t)b * nTP + t) * 64 + d];
  }
}

// ---------------- persistent fused 2-layer LSTM + head ----------------
// Round-18: FENCE-FREE COHERENCE. 2x2 barrier matrix complete: single barrier
// + master/release (r16, 15.2ms) is the sync optimum; skew loses either way.
// Remaining structural cost: TWO buffer_inv per step wipe L1/L2, so every
// global read (stage h0 64KB/blk, vbuf h1, head h1, AND the immutable zqT)
// misses to MALL every step. Change: read mutable state (h0T/h1T) with
// UNCACHED sc0sc1 loads (same memory-side data the WT stores produced; same
// MALL latency the post-inv cached reads already paid) and DELETE both
// fences -> zqT/L2 stay warm, fence serialization gone. Asm discipline:
// no-wait load clusters, one s_waitcnt vmcnt(0) + sched_barrier(0) before
// register consumers (rule #18); =&v outputs; nothing lives across barriers.
// Protocol/order/arithmetic byte-identical to r16 -> absmax 0.0.

__global__ __launch_bounds__(512, 2) void k_lstm(
    const float* __restrict__ zqT,
    const float* __restrict__ wih0, const float* __restrict__ whh0, const float* __restrict__ bl0,
    const float* __restrict__ wih1, const float* __restrict__ whh1, const float* __restrict__ bl1,
    const float* __restrict__ wout, const float* __restrict__ bout,
    float* __restrict__ st, float* __restrict__ out)
{
  __shared__ float wB [2][4][32][36];
  __shared__ float wAh[2][4][32][20];
  __shared__ float wAz[2][4][64];
  __shared__ float wHd[2][512];
  __shared__ float bHd[2];
  __shared__ float h0s[16384];   // staged h0[t-1], XOR-swizzled [512][32]

  float* h0T = st;                          // [2][512][32]
  float* h1T = st + 32768;                  // [2][512][32]
  unsigned* flags = (unsigned*)(st + 65536); // [256] arrival (16 lines)
  unsigned* rel   = flags + 1024;            // [256*16] one private 64B line per block

  const int blk = blockIdx.x;
  const int tid = threadIdx.x;
  const int dim = tid >> 8;
  const int bg  = (tid >> 5) & 7;
  const int c   = tid & 31;
  const int b0  = bg * 4;
  const int j   = 2 * blk + dim;

  // ---- stage weights into LDS ----
  for (int idx = tid; idx < 2 * 4 * 32 * 32; idx += 512) {
    int k = idx & 31, cc = (idx >> 5) & 31, gg = (idx >> 10) & 3, dd = idx >> 12;
    int row = gg * 512 + 2 * blk + dd;
    float v = (cc < 16) ? whh1[(size_t)row * 512 + cc * 32 + k]
                        : wih1[(size_t)row * 512 + (cc - 16) * 32 + k];
    wB[dd][gg][cc][k] = v;
  }
  for (int idx = tid; idx < 2 * 4 * 32 * 16; idx += 512) {
    int k = idx & 15, cc = (idx >> 4) & 31, gg = (idx >> 9) & 3, dd = idx >> 11;
    wAh[dd][gg][cc][k] = whh0[(size_t)(gg * 512 + 2 * blk + dd) * 512 + cc * 16 + k];
  }
  if (tid < 512) {
    int d = tid & 63, gg = (tid >> 6) & 3, dd = tid >> 8;
    wAz[dd][gg][d] = wih0[(size_t)(gg * 512 + 2 * blk + dd) * 64 + d];
  }
  if (blk < 96) {
    for (int idx = tid; idx < 1024; idx += 512) {
      int q = idx >> 9, i = idx & 511;
      int p = blk * 2 + q;
      wHd[q][i] = wout[(size_t)(p >> 5) * 512 + i];
      if (i == 0) bHd[q] = bout[p >> 5];
    }
  }
  float bA[4], bB4[4];
  #pragma unroll
  for (int g = 0; g < 4; g++) { bA[g] = bl0[g * 512 + j]; bB4[g] = bl1[g * 512 + j]; }
  float creg0 = 0.f, creg1 = 0.f;   // cell state for (j, b0+c), lanes c<4 only
  __syncthreads();

  // per-lane swizzled LDS base pointers (swizzle bits 2-4; offsets use bits >=5)
  const float* h0vL0 = h0s + ((c * 512 + b0) ^ ((c & 7) << 2));
  const int cp = c - 16;
  const float* h0vA = h0s + (((cp < 0 ? 0 : cp) * 1024 + b0) ^ (((2 * (cp < 0 ? 0 : cp)) & 7) << 2));
  const float* h0vB = h0s + (((cp < 0 ? 0 : cp) * 1024 + 512 + b0) ^ (((2 * (cp < 0 ? 0 : cp) + 1) & 7) << 2));

  for (int t = 0; t <= nTP + 1; t++) {
    // ---- stage h0[t-1] (uncached memory-side reads) into swizzled LDS ----
    if (t <= nTP) {
      const float* src = h0T + (t & 1) * 16384;
      f32x4v sv[8];
      #pragma unroll
      for (int q = 0; q < 8; q++) sv[q] = load_f32x4_wt_nw(src + (q * 512 + tid) * 4);
      asm volatile("s_waitcnt vmcnt(0)" ::: "memory");
      __builtin_amdgcn_sched_barrier(0);
      #pragma unroll
      for (int q = 0; q < 8; q++) {
        int lin = (q * 512 + tid) * 4;
        int phys = lin ^ (((lin >> 9) & 7) << 2);
        *(f32x4v*)&h0s[phys] = sv[q];
      }
      __syncthreads();
    }

    // ---- L0 step t (h from LDS; zqT cached — stays warm, no fences) ----
    if (t < nTP) {
      float acc[16];
      #pragma unroll
      for (int r = 0; r < 16; r++) acc[r] = 0.f;
      {
        #pragma unroll
        for (int s = 0; s < 4; s++) {
          float4 v0 = *(const float4*)(h0vL0 + (s * 4 + 0) * 32);
          float4 v1 = *(const float4*)(h0vL0 + (s * 4 + 1) * 32);
          float4 v2 = *(const float4*)(h0vL0 + (s * 4 + 2) * 32);
          float4 v3 = *(const float4*)(h0vL0 + (s * 4 + 3) * 32);
          #pragma unroll
          for (int g = 0; g < 4; g++) {
            float4 w = *(const float4*)&wAh[dim][g][c][s * 4];
            float* a = acc + g * 4;
            a[0]=fmaf(w.x,v0.x,a[0]); a[0]=fmaf(w.y,v1.x,a[0]); a[0]=fmaf(w.z,v2.x,a[0]); a[0]=fmaf(w.w,v3.x,a[0]);
            a[1]=fmaf(w.x,v0.y,a[1]); a[1]=fmaf(w.y,v1.y,a[1]); a[1]=fmaf(w.z,v2.y,a[1]); a[1]=fmaf(w.w,v3.y,a[1]);
            a[2]=fmaf(w.x,v0.z,a[2]); a[2]=fmaf(w.y,v1.z,a[2]); a[2]=fmaf(w.z,v2.z,a[2]); a[2]=fmaf(w.w,v3.z,a[2]);
            a[3]=fmaf(w.x,v0.w,a[3]); a[3]=fmaf(w.y,v1.w,a[3]); a[3]=fmaf(w.z,v2.w,a[3]); a[3]=fmaf(w.w,v3.w,a[3]);
          }
        }
      }
      {
        const float* zt = zqT + (size_t)t * 2048 + b0;
        float4 u0 = *(const float4*)(zt + (c * 2 + 0) * 32);
        float4 u1 = *(const float4*)(zt + (c * 2 + 1) * 32);
        #pragma unroll
        for (int g = 0; g < 4; g++) {
          float wx = wAz[dim][g][c * 2 + 0], wy = wAz[dim][g][c * 2 + 1];
          float* a = acc + g * 4;
          a[0]=fmaf(wx,u0.x,a[0]); a[0]=fmaf(wy,u1.x,a[0]);
          a[1]=fmaf(wx,u0.y,a[1]); a[1]=fmaf(wy,u1.y,a[1]);
          a[2]=fmaf(wx,u0.z,a[2]); a[2]=fmaf(wy,u1.z,a[2]);
          a[3]=fmaf(wx,u0.w,a[3]); a[3]=fmaf(wy,u1.w,a[3]);
        }
      }
      // reduce: same tree order m = 1,2,4,8,16 (bit-identical)
      #pragma unroll
      for (int r = 0; r < 16; r++) acc[r] += dpp_xor1(acc[r]);
      #pragma unroll
      for (int r = 0; r < 16; r++) acc[r] += dpp_xor2(acc[r]);
      #pragma unroll
      for (int r = 0; r < 16; r++) acc[r] += swz_xor4(acc[r]);
      #pragma unroll
      for (int r = 0; r < 16; r++) acc[r] += dpp_xor8(acc[r]);
      #pragma unroll
      for (int r = 0; r < 16; r++) acc[r] += swz_xor16(acc[r]);
      if (c < 4) {
        int b = b0 + c;
        float gi = sigmoidf_(acc[0 * 4 + c] + bA[0]);
        float gf = sigmoidf_(acc[1 * 4 + c] + bA[1]);
        float gg = tanhf    (acc[2 * 4 + c] + bA[2]);
        float go = sigmoidf_(acc[3 * 4 + c] + bA[3]);
        float cn = fmaf(gf, creg0, gi * gg);
        creg0 = cn;
        store_f32_wt(h0T + ((t + 1) & 1) * 16384 + j * 32 + b, go * tanhf(cn));
      }
    }

    // ---- L1 step t-1: h1 via uncached in-phase cluster (c<16); h0s LDS (c>=16) ----
    if (t >= 1 && t <= nTP) {
      const float* h1p = h1T + ((t - 1) & 1) * 16384;
      f32x4v vbuf[32];
      if (c < 16) {
        const float* vg = h1p + c * 32 * 32 + b0;
        #pragma unroll
        for (int k = 0; k < 32; k++) vbuf[k] = load_f32x4_wt_nw(vg + k * 32);
      } else {
        #pragma unroll
        for (int k = 0; k < 16; k++) vbuf[k] = *(const f32x4v*)(h0vA + k * 32);
        #pragma unroll
        for (int k = 0; k < 16; k++) vbuf[16 + k] = *(const f32x4v*)(h0vB + k * 32);
      }
      asm volatile("s_waitcnt vmcnt(0)" ::: "memory");
      __builtin_amdgcn_sched_barrier(0);
      float acc[16];
      #pragma unroll
      for (int r = 0; r < 16; r++) acc[r] = 0.f;
      #pragma unroll
      for (int s = 0; s < 8; s++) {
        f32x4v v0 = vbuf[s * 4 + 0];
        f32x4v v1 = vbuf[s * 4 + 1];
        f32x4v v2 = vbuf[s * 4 + 2];
        f32x4v v3 = vbuf[s * 4 + 3];
        #pragma unroll
        for (int g = 0; g < 4; g++) {
          float4 w = *(const float4*)&wB[dim][g][c][s * 4];
          float* a = acc + g * 4;
          a[0]=fmaf(w.x,v0.x,a[0]); a[0]=fmaf(w.y,v1.x,a[0]); a[0]=fmaf(w.z,v2.x,a[0]); a[0]=fmaf(w.w,v3.x,a[0]);
          a[1]=fmaf(w.x,v0.y,a[1]); a[1]=fmaf(w.y,v1.y,a[1]); a[1]=fmaf(w.z,v2.y,a[1]); a[1]=fmaf(w.w,v3.y,a[1]);
          a[2]=fmaf(w.x,v0.z,a[2]); a[2]=fmaf(w.y,v1.z,a[2]); a[2]=fmaf(w.z,v2.z,a[2]); a[2]=fmaf(w.w,v3.z,a[2]);
          a[3]=fmaf(w.x,v0.w,a[3]); a[3]=fmaf(w.y,v1.w,a[3]); a[3]=fmaf(w.z,v2.w,a[3]); a[3]=fmaf(w.w,v3.w,a[3]);
        }
      }
      #pragma unroll
      for (int r = 0; r < 16; r++) acc[r] += dpp_xor1(acc[r]);
      #pragma unroll
      for (int r = 0; r < 16; r++) acc[r] += dpp_xor2(acc[r]);
      #pragma unroll
      for (int r = 0; r < 16; r++) acc[r] += swz_xor4(acc[r]);
      #pragma unroll
      for (int r = 0; r < 16; r++) acc[r] += dpp_xor8(acc[r]);
      #pragma unroll
      for (int r = 0; r < 16; r++) acc[r] += swz_xor16(acc[r]);
      if (c < 4) {
        int b = b0 + c;
        float gi = sigmoidf_(acc[0 * 4 + c] + bB4[0]);
        float gf = sigmoidf_(acc[1 * 4 + c] + bB4[1]);
        float gg = tanhf    (acc[2 * 4 + c] + bB4[2]);
        float go = sigmoidf_(acc[3 * 4 + c] + bB4[3]);
        float cn = fmaf(gf, creg1, gi * gg);
        creg1 = cn;
        store_f32_wt(h1T + (t & 1) * 16384 + j * 32 + b, go * tanhf(cn));
      }
    }

    // drain this wave's loads and write-through stores, then block-wide rendezvous
    asm volatile("s_waitcnt vmcnt(0)" ::: "memory");
    __syncthreads();

    // ---- arrival flag (all waves drained at this point) ----
    if (t <= nTP && tid == 0) store_u32_wt(flags + blk, (unsigned)(t + 1));

    // ---- head for step t-2 on wave 1 (uncached h1 reads), overlapping barrier wait ----
    // STANDALONE guard: must also run at t == nTP+1 (emits output step 1023).
    if (t >= 2 && blk < 96 && tid >= 64 && tid < 80) {
      int q = (tid >> 3) & 1, l = tid & 7;
      int p = blk * 2 + q;
      int b = p & 31;
      const float* h1s = h1T + ((t - 1) & 1) * 16384;   // h1 step t-2 (covered by barrier t-1)
      float hv[64];
      #pragma unroll
      for (int m = 0; m < 64; m++) hv[m] = load_f32_wt_nw(h1s + (l * 64 + m) * 32 + b);
      asm volatile("s_waitcnt vmcnt(0)" ::: "memory");
      __builtin_amdgcn_sched_barrier(0);
      float a = 0.f;
      #pragma unroll
      for (int m = 0; m < 64; m++) a = fmaf(wHd[q][l * 64 + m], hv[m], a);
      a += __shfl_down(a, 4, 8);
      a += __shfl_down(a, 2, 8);
      a += __shfl_down(a, 1, 8);
      if (l == 0) out[((size_t)b * nTP + (t - 2)) * 6 + (p >> 5)] = a + bHd[q];
    }

    // ---- master/release barrier (NO acquire fences: all state reads uncached) ----
    if (t <= nTP) {
      unsigned tgt = (unsigned)(t + 1);
      if (blk == 0) {
        if (tid < 64) {
          const u32x4* fp = (const u32x4*)flags + tid;
          for (;;) {
            u32x4 f;
            asm volatile("global_load_dwordx4 %0, %1, off sc0 sc1\n\ts_waitcnt vmcnt(0)"
                         : "=&v"(f) : "v"(fp) : "memory");
            bool ok = (f.x >= tgt) && (f.y >= tgt) && (f.z >= tgt) && (f.w >= tgt);
            if (__all(ok)) break;
            __builtin_amdgcn_s_sleep(1);
          }
          // release broadcast: each lane owns 4 private 64B lines
          unsigned* rp = rel + tid * 64;
          #pragma unroll
          for (int q = 0; q < 4; q++) store_u32_wt(rp + q * 16, tgt);
        }
      } else {
        if (tid == 0) {
          const unsigned* rp = rel + blk * 16;   // this block's private release line
          while (load_u32_wt(rp) < tgt) __builtin_amdgcn_s_sleep(1);
        }
      }
      __syncthreads();
    }
  }
}

// ---------------- launch ----------------

extern "C" void kernel_launch(void* const* d_in, const int* in_sizes, int n_in,
                              void* d_out, int out_size, void* d_ws, size_t ws_size,
                              hipStream_t stream) {
  (void)in_sizes; (void)n_in; (void)out_size; (void)ws_size;
  const float* x    = (const float*)d_in[0];
  const float* w1   = (const float*)d_in[1];
  const float* b1   = (const float*)d_in[2];
  const float* w2   = (const float*)d_in[3];
  const float* b2   = (const float*)d_in[4];
  const float* w3   = (const float*)d_in[5];
  const float* b3   = (const float*)d_in[6];
  const float* cb   = (const float*)d_in[7];
  const float* wih0 = (const float*)d_in[8];
  const float* whh0 = (const float*)d_in[9];
  const float* bl0  = (const float*)d_in[10];
  const float* wih1 = (const float*)d_in[11];
  const float* whh1 = (const float*)d_in[12];
  const float* bl1  = (const float*)d_in[13];
  const float* wout = (const float*)d_in[14];
  const float* bout = (const float*)d_in[15];
  float* out = (float*)d_out;

  float* ws  = (float*)d_ws;
  // region reuse: st+flags overlaps sig (dead after conv1); zqT overlaps h1c (dead after conv2)
  float* sig = ws;                 // 131072 floats (later: h0T/h1T 65536 + flags/rel)
  float* h1c = sig + 131072;       // 4194304  [32][64][2048] (later: zqT, 2097152)
  float* h2c = h1c + 4194304;      // 2097152  [32][64][1024]
  float* ze  = h2c + 2097152;      // 2097152  [32][64][1024]
  float* zq  = ze  + 2097152;      // 2097152  [32*1024][64]
  float* cbn = zq  + 2097152;      // 256
  float* stp = ws;                 // h0T[2][512][32], h1T[2][512][32], flags[1024], rel[4096]
  float* zqT = h1c;                // 2097152  [1024][64][32]

  k_mean <<<32768, 256, 0, stream>>>(x, sig);
  k_conv1<<<16384, 256, 0, stream>>>(sig, w1, b1, h1c);
  hipMemsetAsync(stp, 0, (65536 + 1024 + 4096) * sizeof(float), stream);  // state + flags + rel
  k_conv2<<<8192, 256, 0, stream>>>(h1c, w2, b2, h2c);
  k_conv3<<<8192, 256, 0, stream>>>(h2c, w3, b3, ze);
  k_cbnorm<<<1, 256, 0, stream>>>(cb, cbn);
  k_vq   <<<128, 256, 0, stream>>>(ze, cb, cbn, zq);
  k_zqt  <<<1024, 256, 0, stream>>>(zq, zqT);   // h1c dead now; write zqT over it

  void* kargs[] = { (void*)&zqT, (void*)&wih0, (void*)&whh0, (void*)&bl0,
                    (void*)&wih1, (void*)&whh1, (void*)&bl1,
                    (void*)&wout, (void*)&bout, (void*)&stp, (void*)&out };
  hipLaunchCooperativeKernel((void*)k_lstm, dim3(256), dim3(512), kargs, 0, stream);
}